// Round 1
// baseline (193.737 us; speedup 1.0000x reference)
//
#include <hip/hip_runtime.h>
#include <stdint.h>

#define DIM 512
#define DH  64
#define NH  8
#define NKV 2
#define NB  4
#define NS  2048
#define TAB (NS*32)

typedef __attribute__((ext_vector_type(8))) short short8;
typedef __attribute__((ext_vector_type(4))) float f32x4;

__device__ __forceinline__ unsigned short f2bf(float f) {
  union { float f; unsigned u; } v; v.f = f;
  return (unsigned short)((v.u + 0x7fffu + ((v.u >> 16) & 1u)) >> 16);
}
__device__ __forceinline__ float bf2f(unsigned short b) {
  union { unsigned u; float f; } v; v.u = ((unsigned)b) << 16;
  return v.f;
}

// ---------- LayerNorm + transpose: x (b,512,2048) f32 -> xn (b*2048, 512) bf16
__global__ __launch_bounds__(256) void ln_kernel(const float* __restrict__ x,
    const float* __restrict__ gamma, const float* __restrict__ beta,
    unsigned short* __restrict__ xn) {
  const int b = blockIdx.y;
  const int n0 = blockIdx.x * 32;
  const int tid = threadIdx.x;
  const int nl = tid & 31, grp = tid >> 5;
  const float* xb = x + (size_t)b * DIM * NS;
  __shared__ float sm[8][32], sq[8][32], mu_s[32], rs_s[32];
  __shared__ float tile[32][33];
  float s = 0.f, s2 = 0.f;
  #pragma unroll 4
  for (int i = 0; i < 64; ++i) {
    float v = xb[(size_t)(grp*64 + i)*NS + n0 + nl];
    s += v; s2 += v*v;
  }
  sm[grp][nl] = s; sq[grp][nl] = s2;
  __syncthreads();
  if (tid < 32) {
    float ts = 0.f, ts2 = 0.f;
    #pragma unroll
    for (int g = 0; g < 8; ++g) { ts += sm[g][tid]; ts2 += sq[g][tid]; }
    float mu = ts * (1.f/512.f);
    float var = ts2 * (1.f/512.f) - mu*mu;
    mu_s[tid] = mu; rs_s[tid] = rsqrtf(var + 1e-5f);
  }
  __syncthreads();
  const float mu = mu_s[nl], rs = rs_s[nl];
  for (int d0 = 0; d0 < DIM; d0 += 32) {
    #pragma unroll
    for (int jj = 0; jj < 4; ++jj) {
      int d = d0 + grp*4 + jj;
      float v = xb[(size_t)d*NS + n0 + nl];
      tile[nl][grp*4 + jj] = (v - mu) * rs * gamma[d] + beta[d];
    }
    __syncthreads();
    if (tid < 128) {
      int ni = tid >> 2, c4 = tid & 3;
      short8 o;
      #pragma unroll
      for (int j = 0; j < 8; ++j) o[j] = (short)f2bf(tile[ni][c4*8 + j]);
      *(short8*)&xn[((size_t)(b*NS + n0 + ni))*DIM + d0 + c4*8] = o;
    }
    __syncthreads();
  }
}

// ---------- weight transpose+convert: Wq|Wkv -> Wqkvt[768][512] bf16, Wout -> Woutt[512][512] bf16
__global__ __launch_bounds__(256) void cvt_kernel(const float* __restrict__ Wq,
    const float* __restrict__ Wkv, const float* __restrict__ Wout,
    unsigned short* __restrict__ Wqkvt, unsigned short* __restrict__ Woutt) {
  __shared__ float t[64][65];
  const int id = blockIdx.x;
  const float* src; int W, k0, c0; unsigned short* dst; int drow0;
  if (id < 64)      { src = Wq;  W = 512; k0 = (id>>3)*64;        c0 = (id&7)*64;        dst = Wqkvt; drow0 = c0; }
  else if (id < 96) { int i2 = id-64; src = Wkv; W = 256; k0 = (i2>>2)*64; c0 = (i2&3)*64; dst = Wqkvt; drow0 = 512 + c0; }
  else              { int i3 = id-96; src = Wout; W = 512; k0 = (i3>>3)*64; c0 = (i3&7)*64; dst = Woutt; drow0 = c0; }
  const int tid = threadIdx.x;
  #pragma unroll 4
  for (int it = 0; it < 16; ++it) {
    int row = it*4 + (tid>>6), col = tid & 63;
    t[row][col] = src[(size_t)(k0+row)*W + c0 + col];
  }
  __syncthreads();
  #pragma unroll 4
  for (int it = 0; it < 16; ++it) {
    int row = it*4 + (tid>>6), col = tid & 63;
    dst[(size_t)(drow0 + row)*512 + k0 + col] = f2bf(t[col][row]);
  }
}

// ---------- rotary tables: cos, sin, qscale(*0.125), kscale(=1/scale), each [2048][32] f32
__global__ __launch_bounds__(256) void tables_kernel(float* __restrict__ tabs) {
  int tix = blockIdx.x*256 + threadIdx.x;
  if (tix >= TAB) return;
  int pos = tix >> 5, i = tix & 31;
  float inv = exp2f(-(float)i * (13.287712379549449f / 32.f));  // 10000^(-2i/64)
  float ang = (float)pos * inv;
  float sv, cv; sincosf(ang, &sv, &cv);
  float base = ((float)(2*i) + 25.6f) / 89.6f;
  float power = ((float)pos - 1024.f) / 4096.f;
  float sc = exp2f(power * log2f(base));
  tabs[tix]         = cv;
  tabs[TAB + tix]   = sv;
  tabs[2*TAB + tix] = sc * 0.125f;   // q scale with 1/sqrt(dh) folded in
  tabs[3*TAB + tix] = 1.f / sc;      // k scale
}

// ---------- QKV GEMM: xn[8192][512] @ Wqkvt^T -> q/k/v with fused xPos rotary
__global__ __launch_bounds__(256) void qkv_kernel(const unsigned short* __restrict__ A,
    const unsigned short* __restrict__ Bt, const float* __restrict__ tabs,
    unsigned short* __restrict__ q, unsigned short* __restrict__ k,
    unsigned short* __restrict__ v) {
  __shared__ __align__(16) short As[128][40];
  __shared__ __align__(16) short Bs[128][40];
  const int m0 = blockIdx.x * 128, ntile = blockIdx.y, n0 = ntile * 128;
  const int tid = threadIdx.x, w = tid >> 6, lane = tid & 63;
  const int wr = w >> 1, wc = w & 1;
  f32x4 acc[4][4];
  #pragma unroll
  for (int i = 0; i < 4; ++i)
    #pragma unroll
    for (int j = 0; j < 4; ++j) acc[i][j] = (f32x4){0.f,0.f,0.f,0.f};
  const int rA = tid >> 2, c8 = (tid & 3) * 8;
  for (int kt = 0; kt < 16; ++kt) {
    short8 a0 = *(const short8*)&A[(size_t)(m0 + rA)*DIM + kt*32 + c8];
    short8 a1 = *(const short8*)&A[(size_t)(m0 + 64 + rA)*DIM + kt*32 + c8];
    short8 b0 = *(const short8*)&Bt[(size_t)(n0 + rA)*DIM + kt*32 + c8];
    short8 b1 = *(const short8*)&Bt[(size_t)(n0 + 64 + rA)*DIM + kt*32 + c8];
    *(short8*)&As[rA][c8] = a0;
    *(short8*)&As[64 + rA][c8] = a1;
    *(short8*)&Bs[rA][c8] = b0;
    *(short8*)&Bs[64 + rA][c8] = b1;
    __syncthreads();
    short8 af[4], bf[4];
    #pragma unroll
    for (int mf = 0; mf < 4; ++mf)
      af[mf] = *(const short8*)&As[wr*64 + mf*16 + (lane & 15)][(lane >> 4)*8];
    #pragma unroll
    for (int nf = 0; nf < 4; ++nf)
      bf[nf] = *(const short8*)&Bs[wc*64 + nf*16 + (lane & 15)][(lane >> 4)*8];
    #pragma unroll
    for (int mf = 0; mf < 4; ++mf)
      #pragma unroll
      for (int nf = 0; nf < 4; ++nf)
        acc[mf][nf] = __builtin_amdgcn_mfma_f32_16x16x32_bf16(af[mf], bf[nf], acc[mf][nf], 0, 0, 0);
    __syncthreads();
  }
  const int mw = m0 + wr*64, cw = n0 + wc*64;
  if (ntile < 4) {              // ---- Q region, rotary * qscale
    #pragma unroll
    for (int nfp = 0; nfp < 2; ++nfp) {
      const int c_lo = cw + nfp*16 + (lane & 15);
      const int head = c_lo >> 6, ii = c_lo & 31;
      const float* tb = tabs + ii;
      #pragma unroll
      for (int mf = 0; mf < 4; ++mf) {
        #pragma unroll
        for (int r = 0; r < 4; ++r) {
          int mm = mw + mf*16 + (lane >> 4)*4 + r;
          int bb = mm >> 11, n = mm & (NS-1);
          float cv = tb[n*32], sv = tb[TAB + n*32], qs = tb[2*TAB + n*32];
          float lo = acc[mf][nfp][r], hi = acc[mf][nfp+2][r];
          size_t base = (((size_t)bb*NH + head)*NS + n)*DH;
          q[base + ii]      = f2bf((lo*cv - hi*sv)*qs);
          q[base + ii + 32] = f2bf((hi*cv + lo*sv)*qs);
        }
      }
    }
  } else if (ntile == 4) {      // ---- K region, rotary * (1/scale)
    #pragma unroll
    for (int nfp = 0; nfp < 2; ++nfp) {
      const int c_lo = cw + nfp*16 + (lane & 15);
      const int kvh = (c_lo - 512) >> 6, ii = c_lo & 31;
      const float* tb = tabs + ii;
      #pragma unroll
      for (int mf = 0; mf < 4; ++mf) {
        #pragma unroll
        for (int r = 0; r < 4; ++r) {
          int mm = mw + mf*16 + (lane >> 4)*4 + r;
          int bb = mm >> 11, n = mm & (NS-1);
          float cv = tb[n*32], sv = tb[TAB + n*32], ks = tb[3*TAB + n*32];
          float lo = acc[mf][nfp][r], hi = acc[mf][nfp+2][r];
          size_t base = (((size_t)bb*NKV + kvh)*NS + n)*DH;
          k[base + ii]      = f2bf((lo*cv - hi*sv)*ks);
          k[base + ii + 32] = f2bf((hi*cv + lo*sv)*ks);
        }
      }
    }
  } else {                      // ---- V region, plain store
    #pragma unroll
    for (int nf = 0; nf < 4; ++nf) {
      const int c = cw + nf*16 + (lane & 15);
      const int kvh = (c - 640) >> 6, dd = c & 63;
      #pragma unroll
      for (int mf = 0; mf < 4; ++mf) {
        #pragma unroll
        for (int r = 0; r < 4; ++r) {
          int mm = mw + mf*16 + (lane >> 4)*4 + r;
          int bb = mm >> 11, n = mm & (NS-1);
          v[(((size_t)bb*NKV + kvh)*NS + n)*DH + dd] = f2bf(acc[mf][nf][r]);
        }
      }
    }
  }
}

// ---------- flash attention: 1 block = (b, h, 64 q-rows), 4 waves x 16 rows
__global__ __launch_bounds__(256) void attn_kernel(const unsigned short* __restrict__ q,
    const unsigned short* __restrict__ kg, const unsigned short* __restrict__ vg,
    unsigned short* __restrict__ ao) {
  __shared__ __align__(16) short kt[64][72];
  __shared__ __align__(16) short vt[64*72];       // transposed V, XOR-swizzled chunks
  __shared__ __align__(16) short pt[4][16][72];
  const int qt = blockIdx.x, h = blockIdx.y, b = blockIdx.z;
  const int kvh = h & (NKV-1);                    // tile semantics: head h -> kv head h%2
  const int q0 = qt * 64;
  const int tid = threadIdx.x, w = tid >> 6, lane = tid & 63;
  const unsigned short* qp = q + (((size_t)b*NH + h)*NS + q0 + w*16 + (lane & 15))*DH + (lane >> 4)*8;
  const short8 aq0 = *(const short8*)qp;
  const short8 aq1 = *(const short8*)(qp + 32);
  const unsigned short* kb = kg + ((size_t)b*NKV + kvh)*NS*DH;
  const unsigned short* vb = vg + ((size_t)b*NKV + kvh)*NS*DH;
  f32x4 o[4];
  float m[4], l[4];
  #pragma unroll
  for (int i = 0; i < 4; ++i) { o[i] = (f32x4){0.f,0.f,0.f,0.f}; m[i] = -1e30f; l[i] = 0.f; }
  for (int ktile = 0; ktile < NS/64; ++ktile) {
    const int k0 = ktile * 64;
    #pragma unroll
    for (int it = 0; it < 2; ++it) {
      int c = it*256 + tid;
      int rk = c >> 3, ck = (c & 7)*8;
      *(short8*)&kt[rk][ck] = *(const short8*)&kb[(size_t)(k0 + rk)*DH + ck];
      int g = c >> 6, rl = c & 7, c8v = (c >> 3) & 7;
      int rv = g*8 + rl;
      short8 vvv = *(const short8*)&vb[(size_t)(k0 + rv)*DH + c8v*8];
      #pragma unroll
      for (int j = 0; j < 8; ++j) {
        int cc = c8v*8 + j;
        *(short*)((char*)vt + (size_t)cc*144 + rl*2 + 16*(g ^ c8v)) = vvv[j];
      }
    }
    __syncthreads();
    f32x4 s[4];
    #pragma unroll
    for (int kf = 0; kf < 4; ++kf) {
      s[kf] = (f32x4){0.f,0.f,0.f,0.f};
      short8 b0 = *(const short8*)&kt[kf*16 + (lane & 15)][(lane >> 4)*8];
      short8 b1 = *(const short8*)&kt[kf*16 + (lane & 15)][32 + (lane >> 4)*8];
      s[kf] = __builtin_amdgcn_mfma_f32_16x16x32_bf16(aq0, b0, s[kf], 0, 0, 0);
      s[kf] = __builtin_amdgcn_mfma_f32_16x16x32_bf16(aq1, b1, s[kf], 0, 0, 0);
    }
    float corr[4];
    #pragma unroll
    for (int r = 0; r < 4; ++r) {
      float mx = fmaxf(fmaxf(s[0][r], s[1][r]), fmaxf(s[2][r], s[3][r]));
      mx = fmaxf(mx, __shfl_xor(mx, 1));
      mx = fmaxf(mx, __shfl_xor(mx, 2));
      mx = fmaxf(mx, __shfl_xor(mx, 4));
      mx = fmaxf(mx, __shfl_xor(mx, 8));
      const float mn = fmaxf(m[r], mx);
      const float co = __expf(m[r] - mn);
      float ls = 0.f;
      #pragma unroll
      for (int kf = 0; kf < 4; ++kf) {
        float p = __expf(s[kf][r] - mn);
        ls += p;
        pt[w][(lane >> 4)*4 + r][kf*16 + (lane & 15)] = (short)f2bf(p);
      }
      ls += __shfl_xor(ls, 1); ls += __shfl_xor(ls, 2);
      ls += __shfl_xor(ls, 4); ls += __shfl_xor(ls, 8);
      l[r] = l[r]*co + ls;
      m[r] = mn;
      corr[r] = co;
    }
    #pragma unroll
    for (int df = 0; df < 4; ++df)
      #pragma unroll
      for (int r = 0; r < 4; ++r) o[df][r] *= corr[r];
    const short8 pa0 = *(const short8*)&pt[w][lane & 15][(lane >> 4)*8];
    const short8 pa1 = *(const short8*)&pt[w][lane & 15][32 + (lane >> 4)*8];
    #pragma unroll
    for (int df = 0; df < 4; ++df) {
      const int cdh = df*16 + (lane & 15);
      const char* vrow = (const char*)vt + (size_t)cdh*144;
      const int sw = (cdh >> 3) & 7;
      short8 b0 = *(const short8*)(vrow + 16*(((lane >> 4))     ^ sw));
      short8 b1 = *(const short8*)(vrow + 16*((4 + (lane >> 4)) ^ sw));
      o[df] = __builtin_amdgcn_mfma_f32_16x16x32_bf16(pa0, b0, o[df], 0, 0, 0);
      o[df] = __builtin_amdgcn_mfma_f32_16x16x32_bf16(pa1, b1, o[df], 0, 0, 0);
    }
    __syncthreads();
  }
  float inv[4];
  #pragma unroll
  for (int r = 0; r < 4; ++r) inv[r] = 1.f / l[r];
  #pragma unroll
  for (int df = 0; df < 4; ++df) {
    const int col = h*DH + df*16 + (lane & 15);
    #pragma unroll
    for (int r = 0; r < 4; ++r) {
      const int n = q0 + w*16 + (lane >> 4)*4 + r;
      ao[((size_t)b*NS + n)*DIM + col] = f2bf(o[df][r] * inv[r]);
    }
  }
}

// ---------- out GEMM: ao[8192][512] @ Woutt^T + xn + bout -> out (b,512,2048) f32
__global__ __launch_bounds__(256) void out_kernel(const unsigned short* __restrict__ A,
    const unsigned short* __restrict__ Bt, const unsigned short* __restrict__ xn,
    const float* __restrict__ bout, float* __restrict__ out) {
  __shared__ __align__(16) short As[128][40];
  __shared__ __align__(16) short Bs[128][40];
  const int m0 = blockIdx.x * 128, n0 = blockIdx.y * 128;
  const int tid = threadIdx.x, w = tid >> 6, lane = tid & 63;
  const int wr = w >> 1, wc = w & 1;
  f32x4 acc[4][4];
  #pragma unroll
  for (int i = 0; i < 4; ++i)
    #pragma unroll
    for (int j = 0; j < 4; ++j) acc[i][j] = (f32x4){0.f,0.f,0.f,0.f};
  const int rA = tid >> 2, c8 = (tid & 3) * 8;
  for (int kt = 0; kt < 16; ++kt) {
    short8 a0 = *(const short8*)&A[(size_t)(m0 + rA)*DIM + kt*32 + c8];
    short8 a1 = *(const short8*)&A[(size_t)(m0 + 64 + rA)*DIM + kt*32 + c8];
    short8 b0 = *(const short8*)&Bt[(size_t)(n0 + rA)*DIM + kt*32 + c8];
    short8 b1 = *(const short8*)&Bt[(size_t)(n0 + 64 + rA)*DIM + kt*32 + c8];
    *(short8*)&As[rA][c8] = a0;
    *(short8*)&As[64 + rA][c8] = a1;
    *(short8*)&Bs[rA][c8] = b0;
    *(short8*)&Bs[64 + rA][c8] = b1;
    __syncthreads();
    short8 af[4], bf[4];
    #pragma unroll
    for (int mf = 0; mf < 4; ++mf)
      af[mf] = *(const short8*)&As[wr*64 + mf*16 + (lane & 15)][(lane >> 4)*8];
    #pragma unroll
    for (int nf = 0; nf < 4; ++nf)
      bf[nf] = *(const short8*)&Bs[wc*64 + nf*16 + (lane & 15)][(lane >> 4)*8];
    #pragma unroll
    for (int mf = 0; mf < 4; ++mf)
      #pragma unroll
      for (int nf = 0; nf < 4; ++nf)
        acc[mf][nf] = __builtin_amdgcn_mfma_f32_16x16x32_bf16(af[mf], bf[nf], acc[mf][nf], 0, 0, 0);
    __syncthreads();
  }
  const int mw = m0 + wr*64, cw = n0 + wc*64;
  #pragma unroll
  for (int nf = 0; nf < 4; ++nf) {
    const int d = cw + nf*16 + (lane & 15);
    const float bo = bout[d];
    #pragma unroll
    for (int mf = 0; mf < 4; ++mf) {
      const int mb = mw + mf*16 + (lane >> 4)*4;
      const int bb = mb >> 11, n = mb & (NS-1);
      f32x4 res;
      #pragma unroll
      for (int r = 0; r < 4; ++r)
        res[r] = acc[mf][nf][r] + bf2f(xn[(size_t)(mb + r)*DIM + d]) + bo;
      *(f32x4*)&out[((size_t)bb*DIM + d)*NS + n] = res;
    }
  }
}

extern "C" void kernel_launch(void* const* d_in, const int* in_sizes, int n_in,
                              void* d_out, int out_size, void* d_ws, size_t ws_size,
                              hipStream_t stream) {
  (void)in_sizes; (void)n_in; (void)out_size; (void)ws_size;
  const float* x     = (const float*)d_in[0];
  const float* gamma = (const float*)d_in[1];
  const float* beta  = (const float*)d_in[2];
  const float* Wq    = (const float*)d_in[3];
  const float* Wkv   = (const float*)d_in[4];
  const float* Wout  = (const float*)d_in[5];
  const float* bout  = (const float*)d_in[6];
  float* out = (float*)d_out;
  char* ws = (char*)d_ws;
  // workspace layout (~30.3 MB total)
  unsigned short* xn    = (unsigned short*)(ws);                         // 8 MB
  unsigned short* qb    = (unsigned short*)(ws + (size_t)(8<<20));       // 8 MB
  unsigned short* kb    = (unsigned short*)(ws + (size_t)(16<<20));      // 2 MB
  unsigned short* vb    = (unsigned short*)(ws + (size_t)(18<<20));      // 2 MB
  unsigned short* ao    = (unsigned short*)(ws + (size_t)(20<<20));      // 8 MB
  unsigned short* wqkvt = (unsigned short*)(ws + (size_t)(28<<20));      // 768 KB
  unsigned short* woutt = (unsigned short*)(ws + (size_t)(28<<20) + 786432); // 512 KB
  float* tabs           = (float*)(ws + (size_t)(28<<20) + 786432 + 524288); // 1 MB

  ln_kernel<<<dim3(64, 4), dim3(256), 0, stream>>>(x, gamma, beta, xn);
  cvt_kernel<<<dim3(160), dim3(256), 0, stream>>>(Wq, Wkv, Wout, wqkvt, woutt);
  tables_kernel<<<dim3(256), dim3(256), 0, stream>>>(tabs);
  qkv_kernel<<<dim3(64, 6), dim3(256), 0, stream>>>(xn, wqkvt, tabs, qb, kb, vb);
  attn_kernel<<<dim3(32, 8, 4), dim3(256), 0, stream>>>(qb, kb, vb, ao);
  out_kernel<<<dim3(64, 4), dim3(256), 0, stream>>>(ao, woutt, xn, bout, out);
}

// Round 2
// 148.842 us; speedup vs baseline: 1.3016x; 1.3016x over previous
//
#include <hip/hip_runtime.h>
#include <stdint.h>

#define DIM 512
#define DH  64
#define NH  8
#define NKV 2
#define NB  4
#define NS  2048
#define TAB (NS*32)

typedef __attribute__((ext_vector_type(8))) short short8;
typedef __attribute__((ext_vector_type(4))) float f32x4;

__device__ __forceinline__ unsigned short f2bf(float f) {
  union { float f; unsigned u; } v; v.f = f;
  return (unsigned short)((v.u + 0x7fffu + ((v.u >> 16) & 1u)) >> 16);
}
__device__ __forceinline__ float bf2f(unsigned short b) {
  union { unsigned u; float f; } v; v.u = ((unsigned)b) << 16;
  return v.f;
}
__device__ __forceinline__ unsigned cvt_pk_bf16(float a, float b) {
  unsigned r;
  asm("v_cvt_pk_bf16_f32 %0, %1, %2" : "=v"(r) : "v"(a), "v"(b));
  return r;
}

// ---------- LayerNorm + transpose: x (b,512,2048) f32 -> xn (b*2048, 512) bf16
__global__ __launch_bounds__(256) void ln_kernel(const float* __restrict__ x,
    const float* __restrict__ gamma, const float* __restrict__ beta,
    unsigned short* __restrict__ xn) {
  const int b = blockIdx.y;
  const int n0 = blockIdx.x * 32;
  const int tid = threadIdx.x;
  const int nl = tid & 31, grp = tid >> 5;
  const float* xb = x + (size_t)b * DIM * NS;
  __shared__ float sm[8][32], sq[8][32], mu_s[32], rs_s[32];
  __shared__ float tile[32][33];
  float s = 0.f, s2 = 0.f;
  #pragma unroll 4
  for (int i = 0; i < 64; ++i) {
    float v = xb[(size_t)(grp*64 + i)*NS + n0 + nl];
    s += v; s2 += v*v;
  }
  sm[grp][nl] = s; sq[grp][nl] = s2;
  __syncthreads();
  if (tid < 32) {
    float ts = 0.f, ts2 = 0.f;
    #pragma unroll
    for (int g = 0; g < 8; ++g) { ts += sm[g][tid]; ts2 += sq[g][tid]; }
    float mu = ts * (1.f/512.f);
    float var = ts2 * (1.f/512.f) - mu*mu;
    mu_s[tid] = mu; rs_s[tid] = rsqrtf(var + 1e-5f);
  }
  __syncthreads();
  const float mu = mu_s[nl], rs = rs_s[nl];
  for (int d0 = 0; d0 < DIM; d0 += 32) {
    #pragma unroll
    for (int jj = 0; jj < 4; ++jj) {
      int d = d0 + grp*4 + jj;
      float v = xb[(size_t)d*NS + n0 + nl];
      tile[nl][grp*4 + jj] = (v - mu) * rs * gamma[d] + beta[d];
    }
    __syncthreads();
    if (tid < 128) {
      int ni = tid >> 2, c4 = tid & 3;
      short8 o;
      #pragma unroll
      for (int j = 0; j < 8; ++j) o[j] = (short)f2bf(tile[ni][c4*8 + j]);
      *(short8*)&xn[((size_t)(b*NS + n0 + ni))*DIM + d0 + c4*8] = o;
    }
    __syncthreads();
  }
}

// ---------- weight transpose+convert
__global__ __launch_bounds__(256) void cvt_kernel(const float* __restrict__ Wq,
    const float* __restrict__ Wkv, const float* __restrict__ Wout,
    unsigned short* __restrict__ Wqkvt, unsigned short* __restrict__ Woutt) {
  __shared__ float t[64][65];
  const int id = blockIdx.x;
  const float* src; int W, k0, c0; unsigned short* dst; int drow0;
  if (id < 64)      { src = Wq;  W = 512; k0 = (id>>3)*64;        c0 = (id&7)*64;        dst = Wqkvt; drow0 = c0; }
  else if (id < 96) { int i2 = id-64; src = Wkv; W = 256; k0 = (i2>>2)*64; c0 = (i2&3)*64; dst = Wqkvt; drow0 = 512 + c0; }
  else              { int i3 = id-96; src = Wout; W = 512; k0 = (i3>>3)*64; c0 = (i3&7)*64; dst = Woutt; drow0 = c0; }
  const int tid = threadIdx.x;
  #pragma unroll 4
  for (int it = 0; it < 16; ++it) {
    int row = it*4 + (tid>>6), col = tid & 63;
    t[row][col] = src[(size_t)(k0+row)*W + c0 + col];
  }
  __syncthreads();
  #pragma unroll 4
  for (int it = 0; it < 16; ++it) {
    int row = it*4 + (tid>>6), col = tid & 63;
    dst[(size_t)(drow0 + row)*512 + k0 + col] = f2bf(t[col][row]);
  }
}

// ---------- rotary tables
__global__ __launch_bounds__(256) void tables_kernel(float* __restrict__ tabs) {
  int tix = blockIdx.x*256 + threadIdx.x;
  if (tix >= TAB) return;
  int pos = tix >> 5, i = tix & 31;
  float inv = exp2f(-(float)i * (13.287712379549449f / 32.f));  // 10000^(-2i/64)
  float ang = (float)pos * inv;
  float sv, cv; sincosf(ang, &sv, &cv);
  float base = ((float)(2*i) + 25.6f) / 89.6f;
  float power = ((float)pos - 1024.f) / 4096.f;
  float sc = exp2f(power * log2f(base));
  tabs[tix]         = cv;
  tabs[TAB + tix]   = sv;
  tabs[2*TAB + tix] = sc * 0.125f;   // q scale with 1/sqrt(dh)
  tabs[3*TAB + tix] = 1.f / sc;      // k scale
}

// ---------- QKV GEMM with fused rotary; V stored transposed + pi-permuted
__global__ __launch_bounds__(256) void qkv_kernel(const unsigned short* __restrict__ A,
    const unsigned short* __restrict__ Bt, const float* __restrict__ tabs,
    unsigned short* __restrict__ q, unsigned short* __restrict__ k,
    unsigned short* __restrict__ v) {
  __shared__ __align__(16) short As[128][40];
  __shared__ __align__(16) short Bs[128][40];
  const int m0 = blockIdx.x * 128, ntile = blockIdx.y, n0 = ntile * 128;
  const int tid = threadIdx.x, w = tid >> 6, lane = tid & 63;
  const int wr = w >> 1, wc = w & 1;
  f32x4 acc[4][4];
  #pragma unroll
  for (int i = 0; i < 4; ++i)
    #pragma unroll
    for (int j = 0; j < 4; ++j) acc[i][j] = (f32x4){0.f,0.f,0.f,0.f};
  const int rA = tid >> 2, c8 = (tid & 3) * 8;
  for (int kt = 0; kt < 16; ++kt) {
    short8 a0 = *(const short8*)&A[(size_t)(m0 + rA)*DIM + kt*32 + c8];
    short8 a1 = *(const short8*)&A[(size_t)(m0 + 64 + rA)*DIM + kt*32 + c8];
    short8 b0 = *(const short8*)&Bt[(size_t)(n0 + rA)*DIM + kt*32 + c8];
    short8 b1 = *(const short8*)&Bt[(size_t)(n0 + 64 + rA)*DIM + kt*32 + c8];
    *(short8*)&As[rA][c8] = a0;
    *(short8*)&As[64 + rA][c8] = a1;
    *(short8*)&Bs[rA][c8] = b0;
    *(short8*)&Bs[64 + rA][c8] = b1;
    __syncthreads();
    short8 af[4], bf[4];
    #pragma unroll
    for (int mf = 0; mf < 4; ++mf)
      af[mf] = *(const short8*)&As[wr*64 + mf*16 + (lane & 15)][(lane >> 4)*8];
    #pragma unroll
    for (int nf = 0; nf < 4; ++nf)
      bf[nf] = *(const short8*)&Bs[wc*64 + nf*16 + (lane & 15)][(lane >> 4)*8];
    #pragma unroll
    for (int mf = 0; mf < 4; ++mf)
      #pragma unroll
      for (int nf = 0; nf < 4; ++nf)
        acc[mf][nf] = __builtin_amdgcn_mfma_f32_16x16x32_bf16(af[mf], bf[nf], acc[mf][nf], 0, 0, 0);
    __syncthreads();
  }
  const int mw = m0 + wr*64, cw = n0 + wc*64;
  if (ntile < 4) {              // ---- Q, rotary * qscale
    #pragma unroll
    for (int nfp = 0; nfp < 2; ++nfp) {
      const int c_lo = cw + nfp*16 + (lane & 15);
      const int head = c_lo >> 6, ii = c_lo & 31;
      const float* tb = tabs + ii;
      #pragma unroll
      for (int mf = 0; mf < 4; ++mf) {
        #pragma unroll
        for (int r = 0; r < 4; ++r) {
          int mm = mw + mf*16 + (lane >> 4)*4 + r;
          int bb = mm >> 11, n = mm & (NS-1);
          float cv = tb[n*32], sv = tb[TAB + n*32], qs = tb[2*TAB + n*32];
          float lo = acc[mf][nfp][r], hi = acc[mf][nfp+2][r];
          size_t base = (((size_t)bb*NH + head)*NS + n)*DH;
          q[base + ii]      = f2bf((lo*cv - hi*sv)*qs);
          q[base + ii + 32] = f2bf((hi*cv + lo*sv)*qs);
        }
      }
    }
  } else if (ntile == 4) {      // ---- K, rotary * (1/scale)
    #pragma unroll
    for (int nfp = 0; nfp < 2; ++nfp) {
      const int c_lo = cw + nfp*16 + (lane & 15);
      const int kvh = (c_lo - 512) >> 6, ii = c_lo & 31;
      const float* tb = tabs + ii;
      #pragma unroll
      for (int mf = 0; mf < 4; ++mf) {
        #pragma unroll
        for (int r = 0; r < 4; ++r) {
          int mm = mw + mf*16 + (lane >> 4)*4 + r;
          int bb = mm >> 11, n = mm & (NS-1);
          float cv = tb[n*32], sv = tb[TAB + n*32], ks = tb[3*TAB + n*32];
          float lo = acc[mf][nfp][r], hi = acc[mf][nfp+2][r];
          size_t base = (((size_t)bb*NKV + kvh)*NS + n)*DH;
          k[base + ii]      = f2bf((lo*cv - hi*sv)*ks);
          k[base + ii + 32] = f2bf((hi*cv + lo*sv)*ks);
        }
      }
    }
  } else {                      // ---- V: store transposed [b][kvh][d][n], pi-permuted in 64-tiles
    #pragma unroll
    for (int nf = 0; nf < 4; ++nf) {
      const int c = cw + nf*16 + (lane & 15);
      const int rel = c - 640;
      const int kvh = rel >> 6, dd = rel & 63;
      #pragma unroll
      for (int mf = 0; mf < 4; ++mf) {
        #pragma unroll
        for (int r = 0; r < 4; ++r) {
          int mm = mw + mf*16 + (lane >> 4)*4 + r;
          int bb = mm >> 11, n = mm & (NS-1);
          int pcol = (n & ~63) | (((n & 15) << 2) | ((n >> 4) & 3));
          v[(((size_t)bb*NKV + kvh)*DH + dd)*NS + pcol] = f2bf(acc[mf][nf][r]);
        }
      }
    }
  }
}

// ---------- flash attention: 512 blocks, 8 waves, 128 q-rows/block, dbuf K/V^T
__global__ __launch_bounds__(512, 4) void attn_kernel(const unsigned short* __restrict__ q,
    const unsigned short* __restrict__ kg, const unsigned short* __restrict__ vtp,
    unsigned short* __restrict__ ao) {
  __shared__ __align__(16) short kt[2][64][72];
  __shared__ __align__(16) short vt[2][64][72];
  __shared__ __align__(16) short pt[8][16][72];
  const int bid = blockIdx.x;
  const int dsr = (bid & 7) * 64 + (bid >> 3);     // XCD-chunk swizzle (512 % 8 == 0)
  const int qt = dsr & 15, bh = dsr >> 4;
  const int h = bh & 7, b = bh >> 3;
  const int kvh = h & (NKV-1);                      // tile semantics: head h -> kv head h%2
  const int q0 = qt * 128;
  const int tid = threadIdx.x, w = tid >> 6, lane = tid & 63;
  const unsigned short* qp = q + (((size_t)b*NH + h)*NS + q0 + w*16 + (lane & 15))*DH + (lane >> 4)*8;
  const short8 aq0 = *(const short8*)qp;
  const short8 aq1 = *(const short8*)(qp + 32);
  const unsigned short* kb = kg + ((size_t)b*NKV + kvh)*NS*DH;
  const unsigned short* vb = vtp + ((size_t)b*NKV + kvh)*DH*NS;
  const int srow = tid >> 3, scol = (tid & 7) * 8;
  // prologue: stage tile 0, prefetch tile 1 into regs
  short8 kr = *(const short8*)&kb[(size_t)srow*DH + scol];
  short8 vr = *(const short8*)&vb[(size_t)srow*NS + scol];
  *(short8*)&kt[0][srow][scol] = kr;
  *(short8*)&vt[0][srow][scol] = vr;
  kr = *(const short8*)&kb[(size_t)(64 + srow)*DH + scol];
  vr = *(const short8*)&vb[(size_t)srow*NS + 64 + scol];
  f32x4 o[4];
  float m[4], l[4], corr[4];
  #pragma unroll
  for (int i = 0; i < 4; ++i) { o[i] = (f32x4){0.f,0.f,0.f,0.f}; m[i] = -1e30f; l[i] = 0.f; }
  __syncthreads();
  for (int t = 0; t < 32; ++t) {
    const int cur = t & 1;
    // ---- QK^T
    f32x4 s[4];
    #pragma unroll
    for (int kf = 0; kf < 4; ++kf) {
      short8 b0 = *(const short8*)&kt[cur][kf*16 + (lane & 15)][(lane >> 4)*8];
      short8 b1 = *(const short8*)&kt[cur][kf*16 + (lane & 15)][32 + (lane >> 4)*8];
      s[kf] = (f32x4){0.f,0.f,0.f,0.f};
      s[kf] = __builtin_amdgcn_mfma_f32_16x16x32_bf16(aq0, b0, s[kf], 0, 0, 0);
      s[kf] = __builtin_amdgcn_mfma_f32_16x16x32_bf16(aq1, b1, s[kf], 0, 0, 0);
    }
    // ---- online softmax (sum-reduce deferred to the end; co is row-uniform)
    #pragma unroll
    for (int r = 0; r < 4; ++r) {
      float mx = fmaxf(fmaxf(s[0][r], s[1][r]), fmaxf(s[2][r], s[3][r]));
      mx = fmaxf(mx, __shfl_xor(mx, 1));
      mx = fmaxf(mx, __shfl_xor(mx, 2));
      mx = fmaxf(mx, __shfl_xor(mx, 4));
      mx = fmaxf(mx, __shfl_xor(mx, 8));
      const float mn = fmaxf(m[r], mx);
      const float co = __expf(m[r] - mn);
      float p0 = __expf(s[0][r] - mn);
      float p1 = __expf(s[1][r] - mn);
      float p2 = __expf(s[2][r] - mn);
      float p3 = __expf(s[3][r] - mn);
      l[r] = l[r]*co + (p0 + p1 + p2 + p3);
      unsigned w0 = cvt_pk_bf16(p0, p1);
      unsigned w1 = cvt_pk_bf16(p2, p3);
      *(uint2*)&pt[w][(lane >> 4)*4 + r][(lane & 15)*4] = make_uint2(w0, w1);
      m[r] = mn; corr[r] = co;
    }
    #pragma unroll
    for (int df = 0; df < 4; ++df)
      #pragma unroll
      for (int r = 0; r < 4; ++r) o[df][r] *= corr[r];
    // ---- PV (positions are pi-permuted consistently in pt and vt)
    const short8 pa0 = *(const short8*)&pt[w][lane & 15][(lane >> 4)*8];
    const short8 pa1 = *(const short8*)&pt[w][lane & 15][32 + (lane >> 4)*8];
    #pragma unroll
    for (int df = 0; df < 4; ++df) {
      const int cdh = df*16 + (lane & 15);
      short8 b0 = *(const short8*)&vt[cur][cdh][(lane >> 4)*8];
      short8 b1 = *(const short8*)&vt[cur][cdh][32 + (lane >> 4)*8];
      o[df] = __builtin_amdgcn_mfma_f32_16x16x32_bf16(pa0, b0, o[df], 0, 0, 0);
      o[df] = __builtin_amdgcn_mfma_f32_16x16x32_bf16(pa1, b1, o[df], 0, 0, 0);
    }
    __syncthreads();
    if (t < 31) {
      *(short8*)&kt[cur^1][srow][scol] = kr;
      *(short8*)&vt[cur^1][srow][scol] = vr;
      if (t < 30) {
        const int k2 = (t + 2) * 64;
        kr = *(const short8*)&kb[(size_t)(k2 + srow)*DH + scol];
        vr = *(const short8*)&vb[(size_t)srow*NS + k2 + scol];
      }
      __syncthreads();
    }
  }
  // final denominator reduce across the 16-lane row group
  #pragma unroll
  for (int r = 0; r < 4; ++r) {
    float ls = l[r];
    ls += __shfl_xor(ls, 1);
    ls += __shfl_xor(ls, 2);
    ls += __shfl_xor(ls, 4);
    ls += __shfl_xor(ls, 8);
    l[r] = 1.f / ls;
  }
  #pragma unroll
  for (int df = 0; df < 4; ++df) {
    const int col = h*DH + df*16 + (lane & 15);
    #pragma unroll
    for (int r = 0; r < 4; ++r) {
      const int n = q0 + w*16 + (lane >> 4)*4 + r;
      ao[((size_t)b*NS + n)*DIM + col] = f2bf(o[df][r] * l[r]);
    }
  }
}

// ---------- out GEMM: ao @ Woutt^T + xn + bout -> out (b,512,2048) f32
__global__ __launch_bounds__(256) void out_kernel(const unsigned short* __restrict__ A,
    const unsigned short* __restrict__ Bt, const unsigned short* __restrict__ xn,
    const float* __restrict__ bout, float* __restrict__ out) {
  __shared__ __align__(16) short As[128][40];
  __shared__ __align__(16) short Bs[128][40];
  const int m0 = blockIdx.x * 128, n0 = blockIdx.y * 128;
  const int tid = threadIdx.x, w = tid >> 6, lane = tid & 63;
  const int wr = w >> 1, wc = w & 1;
  f32x4 acc[4][4];
  #pragma unroll
  for (int i = 0; i < 4; ++i)
    #pragma unroll
    for (int j = 0; j < 4; ++j) acc[i][j] = (f32x4){0.f,0.f,0.f,0.f};
  const int rA = tid >> 2, c8 = (tid & 3) * 8;
  for (int kt = 0; kt < 16; ++kt) {
    short8 a0 = *(const short8*)&A[(size_t)(m0 + rA)*DIM + kt*32 + c8];
    short8 a1 = *(const short8*)&A[(size_t)(m0 + 64 + rA)*DIM + kt*32 + c8];
    short8 b0 = *(const short8*)&Bt[(size_t)(n0 + rA)*DIM + kt*32 + c8];
    short8 b1 = *(const short8*)&Bt[(size_t)(n0 + 64 + rA)*DIM + kt*32 + c8];
    *(short8*)&As[rA][c8] = a0;
    *(short8*)&As[64 + rA][c8] = a1;
    *(short8*)&Bs[rA][c8] = b0;
    *(short8*)&Bs[64 + rA][c8] = b1;
    __syncthreads();
    short8 af[4], bf[4];
    #pragma unroll
    for (int mf = 0; mf < 4; ++mf)
      af[mf] = *(const short8*)&As[wr*64 + mf*16 + (lane & 15)][(lane >> 4)*8];
    #pragma unroll
    for (int nf = 0; nf < 4; ++nf)
      bf[nf] = *(const short8*)&Bs[wc*64 + nf*16 + (lane & 15)][(lane >> 4)*8];
    #pragma unroll
    for (int mf = 0; mf < 4; ++mf)
      #pragma unroll
      for (int nf = 0; nf < 4; ++nf)
        acc[mf][nf] = __builtin_amdgcn_mfma_f32_16x16x32_bf16(af[mf], bf[nf], acc[mf][nf], 0, 0, 0);
    __syncthreads();
  }
  const int mw = m0 + wr*64, cw = n0 + wc*64;
  #pragma unroll
  for (int nf = 0; nf < 4; ++nf) {
    const int d = cw + nf*16 + (lane & 15);
    const float bo = bout[d];
    #pragma unroll
    for (int mf = 0; mf < 4; ++mf) {
      const int mb = mw + mf*16 + (lane >> 4)*4;
      const int bb = mb >> 11, n = mb & (NS-1);
      f32x4 res;
      #pragma unroll
      for (int r = 0; r < 4; ++r)
        res[r] = acc[mf][nf][r] + bf2f(xn[(size_t)(mb + r)*DIM + d]) + bo;
      *(f32x4*)&out[((size_t)bb*DIM + d)*NS + n] = res;
    }
  }
}

extern "C" void kernel_launch(void* const* d_in, const int* in_sizes, int n_in,
                              void* d_out, int out_size, void* d_ws, size_t ws_size,
                              hipStream_t stream) {
  (void)in_sizes; (void)n_in; (void)out_size; (void)ws_size;
  const float* x     = (const float*)d_in[0];
  const float* gamma = (const float*)d_in[1];
  const float* beta  = (const float*)d_in[2];
  const float* Wq    = (const float*)d_in[3];
  const float* Wkv   = (const float*)d_in[4];
  const float* Wout  = (const float*)d_in[5];
  const float* bout  = (const float*)d_in[6];
  float* out = (float*)d_out;
  char* ws = (char*)d_ws;
  unsigned short* xn    = (unsigned short*)(ws);                         // 8 MB
  unsigned short* qb    = (unsigned short*)(ws + (size_t)(8<<20));       // 8 MB
  unsigned short* kb    = (unsigned short*)(ws + (size_t)(16<<20));      // 2 MB
  unsigned short* vb    = (unsigned short*)(ws + (size_t)(18<<20));      // 2 MB (V^T, pi-permuted)
  unsigned short* ao    = (unsigned short*)(ws + (size_t)(20<<20));      // 8 MB
  unsigned short* wqkvt = (unsigned short*)(ws + (size_t)(28<<20));      // 768 KB
  unsigned short* woutt = (unsigned short*)(ws + (size_t)(28<<20) + 786432); // 512 KB
  float* tabs           = (float*)(ws + (size_t)(28<<20) + 786432 + 524288); // 1 MB

  ln_kernel<<<dim3(64, 4), dim3(256), 0, stream>>>(x, gamma, beta, xn);
  cvt_kernel<<<dim3(160), dim3(256), 0, stream>>>(Wq, Wkv, Wout, wqkvt, woutt);
  tables_kernel<<<dim3(256), dim3(256), 0, stream>>>(tabs);
  qkv_kernel<<<dim3(64, 6), dim3(256), 0, stream>>>(xn, wqkvt, tabs, qb, kb, vb);
  attn_kernel<<<dim3(512), dim3(512), 0, stream>>>(qb, kb, vb, ao);
  out_kernel<<<dim3(64, 4), dim3(256), 0, stream>>>(ao, woutt, xn, bout, out);
}

// Round 3
// 127.854 us; speedup vs baseline: 1.5153x; 1.1641x over previous
//
#include <hip/hip_runtime.h>
#include <stdint.h>

#define DIM 512
#define DH  64
#define NH  8
#define NKV 2
#define NB  4
#define NS  2048
#define TAB (NS*32)

typedef __attribute__((ext_vector_type(8))) short short8;
typedef __attribute__((ext_vector_type(4))) float f32x4;

__device__ __forceinline__ unsigned short f2bf(float f) {
  union { float f; unsigned u; } v; v.f = f;
  return (unsigned short)((v.u + 0x7fffu + ((v.u >> 16) & 1u)) >> 16);
}
__device__ __forceinline__ float bf2f(unsigned short b) {
  union { unsigned u; float f; } v; v.u = ((unsigned)b) << 16;
  return v.f;
}
__device__ __forceinline__ unsigned cvt_pk_bf16(float a, float b) {
  unsigned r;
  asm("v_cvt_pk_bf16_f32 %0, %1, %2" : "=v"(r) : "v"(a), "v"(b));
  return r;
}

// ---------- LayerNorm + transpose: x (b,512,2048) f32 -> xn (b*2048, 512) bf16
__global__ __launch_bounds__(256) void ln_kernel(const float* __restrict__ x,
    const float* __restrict__ gamma, const float* __restrict__ beta,
    unsigned short* __restrict__ xn) {
  const int b = blockIdx.y;
  const int n0 = blockIdx.x * 32;
  const int tid = threadIdx.x;
  const int nl = tid & 31, grp = tid >> 5;
  const float* xb = x + (size_t)b * DIM * NS;
  __shared__ float sm[8][32], sq[8][32], mu_s[32], rs_s[32];
  __shared__ float tile[32][33];
  float s = 0.f, s2 = 0.f;
  #pragma unroll 4
  for (int i = 0; i < 64; ++i) {
    float v = xb[(size_t)(grp*64 + i)*NS + n0 + nl];
    s += v; s2 += v*v;
  }
  sm[grp][nl] = s; sq[grp][nl] = s2;
  __syncthreads();
  if (tid < 32) {
    float ts = 0.f, ts2 = 0.f;
    #pragma unroll
    for (int g = 0; g < 8; ++g) { ts += sm[g][tid]; ts2 += sq[g][tid]; }
    float mu = ts * (1.f/512.f);
    float var = ts2 * (1.f/512.f) - mu*mu;
    mu_s[tid] = mu; rs_s[tid] = rsqrtf(var + 1e-5f);
  }
  __syncthreads();
  const float mu = mu_s[nl], rs = rs_s[nl];
  for (int d0 = 0; d0 < DIM; d0 += 32) {
    #pragma unroll
    for (int jj = 0; jj < 4; ++jj) {
      int d = d0 + grp*4 + jj;
      float v = xb[(size_t)d*NS + n0 + nl];
      tile[nl][grp*4 + jj] = (v - mu) * rs * gamma[d] + beta[d];
    }
    __syncthreads();
    if (tid < 128) {
      int ni = tid >> 2, c4 = tid & 3;
      short8 o;
      #pragma unroll
      for (int j = 0; j < 8; ++j) o[j] = (short)f2bf(tile[ni][c4*8 + j]);
      *(short8*)&xn[((size_t)(b*NS + n0 + ni))*DIM + d0 + c4*8] = o;
    }
    __syncthreads();
  }
}

// ---------- weight transpose+convert
__global__ __launch_bounds__(256) void cvt_kernel(const float* __restrict__ Wq,
    const float* __restrict__ Wkv, const float* __restrict__ Wout,
    unsigned short* __restrict__ Wqkvt, unsigned short* __restrict__ Woutt) {
  __shared__ float t[64][65];
  const int id = blockIdx.x;
  const float* src; int W, k0, c0; unsigned short* dst; int drow0;
  if (id < 64)      { src = Wq;  W = 512; k0 = (id>>3)*64;        c0 = (id&7)*64;        dst = Wqkvt; drow0 = c0; }
  else if (id < 96) { int i2 = id-64; src = Wkv; W = 256; k0 = (i2>>2)*64; c0 = (i2&3)*64; dst = Wqkvt; drow0 = 512 + c0; }
  else              { int i3 = id-96; src = Wout; W = 512; k0 = (i3>>3)*64; c0 = (i3&7)*64; dst = Woutt; drow0 = c0; }
  const int tid = threadIdx.x;
  #pragma unroll 4
  for (int it = 0; it < 16; ++it) {
    int row = it*4 + (tid>>6), col = tid & 63;
    t[row][col] = src[(size_t)(k0+row)*W + c0 + col];
  }
  __syncthreads();
  #pragma unroll 4
  for (int it = 0; it < 16; ++it) {
    int row = it*4 + (tid>>6), col = tid & 63;
    dst[(size_t)(drow0 + row)*512 + k0 + col] = f2bf(t[col][row]);
  }
}

// ---------- rotary tables (q-scale carries 0.125 * log2(e) for exp2-domain softmax)
__global__ __launch_bounds__(256) void tables_kernel(float* __restrict__ tabs) {
  int tix = blockIdx.x*256 + threadIdx.x;
  if (tix >= TAB) return;
  int pos = tix >> 5, i = tix & 31;
  float inv = exp2f(-(float)i * (13.287712379549449f / 32.f));  // 10000^(-2i/64)
  float ang = (float)pos * inv;
  float sv, cv; sincosf(ang, &sv, &cv);
  float base = ((float)(2*i) + 25.6f) / 89.6f;
  float power = ((float)pos - 1024.f) / 4096.f;
  float sc = exp2f(power * log2f(base));
  tabs[tix]         = cv;
  tabs[TAB + tix]   = sv;
  tabs[2*TAB + tix] = sc * 0.125f * 1.4426950408889634f;  // qscale * 1/sqrt(dh) * log2e
  tabs[3*TAB + tix] = 1.f / sc;                           // k scale
}

// ---------- QKV GEMM with fused rotary; V stored transposed + pi-permuted
__global__ __launch_bounds__(256) void qkv_kernel(const unsigned short* __restrict__ A,
    const unsigned short* __restrict__ Bt, const float* __restrict__ tabs,
    unsigned short* __restrict__ q, unsigned short* __restrict__ k,
    unsigned short* __restrict__ v) {
  __shared__ __align__(16) short As[128][40];
  __shared__ __align__(16) short Bs[128][40];
  const int m0 = blockIdx.x * 128, ntile = blockIdx.y, n0 = ntile * 128;
  const int tid = threadIdx.x, w = tid >> 6, lane = tid & 63;
  const int wr = w >> 1, wc = w & 1;
  f32x4 acc[4][4];
  #pragma unroll
  for (int i = 0; i < 4; ++i)
    #pragma unroll
    for (int j = 0; j < 4; ++j) acc[i][j] = (f32x4){0.f,0.f,0.f,0.f};
  const int rA = tid >> 2, c8 = (tid & 3) * 8;
  for (int kt = 0; kt < 16; ++kt) {
    short8 a0 = *(const short8*)&A[(size_t)(m0 + rA)*DIM + kt*32 + c8];
    short8 a1 = *(const short8*)&A[(size_t)(m0 + 64 + rA)*DIM + kt*32 + c8];
    short8 b0 = *(const short8*)&Bt[(size_t)(n0 + rA)*DIM + kt*32 + c8];
    short8 b1 = *(const short8*)&Bt[(size_t)(n0 + 64 + rA)*DIM + kt*32 + c8];
    *(short8*)&As[rA][c8] = a0;
    *(short8*)&As[64 + rA][c8] = a1;
    *(short8*)&Bs[rA][c8] = b0;
    *(short8*)&Bs[64 + rA][c8] = b1;
    __syncthreads();
    short8 af[4], bf[4];
    #pragma unroll
    for (int mf = 0; mf < 4; ++mf)
      af[mf] = *(const short8*)&As[wr*64 + mf*16 + (lane & 15)][(lane >> 4)*8];
    #pragma unroll
    for (int nf = 0; nf < 4; ++nf)
      bf[nf] = *(const short8*)&Bs[wc*64 + nf*16 + (lane & 15)][(lane >> 4)*8];
    #pragma unroll
    for (int mf = 0; mf < 4; ++mf)
      #pragma unroll
      for (int nf = 0; nf < 4; ++nf)
        acc[mf][nf] = __builtin_amdgcn_mfma_f32_16x16x32_bf16(af[mf], bf[nf], acc[mf][nf], 0, 0, 0);
    __syncthreads();
  }
  const int mw = m0 + wr*64, cw = n0 + wc*64;
  if (ntile < 4) {              // ---- Q, rotary * qscale (exp2-domain)
    #pragma unroll
    for (int nfp = 0; nfp < 2; ++nfp) {
      const int c_lo = cw + nfp*16 + (lane & 15);
      const int head = c_lo >> 6, ii = c_lo & 31;
      const float* tb = tabs + ii;
      #pragma unroll
      for (int mf = 0; mf < 4; ++mf) {
        #pragma unroll
        for (int r = 0; r < 4; ++r) {
          int mm = mw + mf*16 + (lane >> 4)*4 + r;
          int bb = mm >> 11, n = mm & (NS-1);
          float cv = tb[n*32], sv = tb[TAB + n*32], qs = tb[2*TAB + n*32];
          float lo = acc[mf][nfp][r], hi = acc[mf][nfp+2][r];
          size_t base = (((size_t)bb*NH + head)*NS + n)*DH;
          q[base + ii]      = f2bf((lo*cv - hi*sv)*qs);
          q[base + ii + 32] = f2bf((hi*cv + lo*sv)*qs);
        }
      }
    }
  } else if (ntile == 4) {      // ---- K, rotary * (1/scale)
    #pragma unroll
    for (int nfp = 0; nfp < 2; ++nfp) {
      const int c_lo = cw + nfp*16 + (lane & 15);
      const int kvh = (c_lo - 512) >> 6, ii = c_lo & 31;
      const float* tb = tabs + ii;
      #pragma unroll
      for (int mf = 0; mf < 4; ++mf) {
        #pragma unroll
        for (int r = 0; r < 4; ++r) {
          int mm = mw + mf*16 + (lane >> 4)*4 + r;
          int bb = mm >> 11, n = mm & (NS-1);
          float cv = tb[n*32], sv = tb[TAB + n*32], ks = tb[3*TAB + n*32];
          float lo = acc[mf][nfp][r], hi = acc[mf][nfp+2][r];
          size_t base = (((size_t)bb*NKV + kvh)*NS + n)*DH;
          k[base + ii]      = f2bf((lo*cv - hi*sv)*ks);
          k[base + ii + 32] = f2bf((hi*cv + lo*sv)*ks);
        }
      }
    }
  } else {                      // ---- V: store transposed [b][kvh][d][n], pi-permuted in 64-tiles
    #pragma unroll
    for (int nf = 0; nf < 4; ++nf) {
      const int c = cw + nf*16 + (lane & 15);
      const int rel = c - 640;
      const int kvh = rel >> 6, dd = rel & 63;
      #pragma unroll
      for (int mf = 0; mf < 4; ++mf) {
        #pragma unroll
        for (int r = 0; r < 4; ++r) {
          int mm = mw + mf*16 + (lane >> 4)*4 + r;
          int bb = mm >> 11, n = mm & (NS-1);
          int pcol = (n & ~63) | (((n & 15) << 2) | ((n >> 4) & 3));
          v[(((size_t)bb*NKV + kvh)*DH + dd)*NS + pcol] = f2bf(acc[mf][nf][r]);
        }
      }
    }
  }
}

// ---------- flash attention: 512 blocks, 4 waves x 32 q-rows, max-free exp2 softmax
__global__ __launch_bounds__(256, 2) void attn_kernel(const unsigned short* __restrict__ q,
    const unsigned short* __restrict__ kg, const unsigned short* __restrict__ vtp,
    unsigned short* __restrict__ ao) {
  __shared__ __align__(16) short kt[2][64][72];
  __shared__ __align__(16) short vt[2][64][72];
  __shared__ __align__(16) short pt[4][32][72];
  const int bid = blockIdx.x;
  const int dsr = (bid & 7) * 64 + (bid >> 3);     // XCD-chunk swizzle (512 % 8 == 0)
  const int qt = dsr & 15, bh = dsr >> 4;
  const int h = bh & 7, b = bh >> 3;
  const int kvh = h & (NKV-1);                      // tile semantics: head h -> kv head h%2
  const int q0 = qt * 128;
  const int tid = threadIdx.x, w = tid >> 6, lane = tid & 63;
  // Q fragments: 2 m-groups x 2 k-halves (q-scale already has 0.125*log2e)
  short8 aq[2][2];
  const unsigned short* qbase = q + (((size_t)b*NH + h)*NS + q0 + w*32)*DH;
  #pragma unroll
  for (int mg = 0; mg < 2; ++mg) {
    const unsigned short* qp = qbase + (size_t)(mg*16 + (lane & 15))*DH + (lane >> 4)*8;
    aq[mg][0] = *(const short8*)qp;
    aq[mg][1] = *(const short8*)(qp + 32);
  }
  const unsigned short* kb = kg + ((size_t)b*NKV + kvh)*NS*DH;
  const unsigned short* vb = vtp + ((size_t)b*NKV + kvh)*DH*NS;
  const int srow = tid >> 2, scol = (tid & 3) * 16;
  // stage tile 0
  *(short8*)&kt[0][srow][scol]     = *(const short8*)&kb[(size_t)srow*DH + scol];
  *(short8*)&kt[0][srow][scol + 8] = *(const short8*)&kb[(size_t)srow*DH + scol + 8];
  *(short8*)&vt[0][srow][scol]     = *(const short8*)&vb[(size_t)srow*NS + scol];
  *(short8*)&vt[0][srow][scol + 8] = *(const short8*)&vb[(size_t)srow*NS + scol + 8];
  // prefetch tile 1 into regs
  short8 kr0 = *(const short8*)&kb[(size_t)(64 + srow)*DH + scol];
  short8 kr1 = *(const short8*)&kb[(size_t)(64 + srow)*DH + scol + 8];
  short8 vr0 = *(const short8*)&vb[(size_t)srow*NS + 64 + scol];
  short8 vr1 = *(const short8*)&vb[(size_t)srow*NS + 64 + scol + 8];
  f32x4 o[2][4];
  float l[2][4];
  #pragma unroll
  for (int mg = 0; mg < 2; ++mg) {
    #pragma unroll
    for (int i = 0; i < 4; ++i) { o[mg][i] = (f32x4){0.f,0.f,0.f,0.f}; l[mg][i] = 0.f; }
  }
  __syncthreads();
  for (int t = 0; t < 32; ++t) {
    const int cur = t & 1;
    // ---- K fragments (shared across both m-groups)
    short8 kf0[4], kf1[4];
    #pragma unroll
    for (int kf = 0; kf < 4; ++kf) {
      kf0[kf] = *(const short8*)&kt[cur][kf*16 + (lane & 15)][(lane >> 4)*8];
      kf1[kf] = *(const short8*)&kt[cur][kf*16 + (lane & 15)][32 + (lane >> 4)*8];
    }
    // ---- QK^T
    f32x4 s[2][4];
    __builtin_amdgcn_s_setprio(1);
    #pragma unroll
    for (int mg = 0; mg < 2; ++mg)
      #pragma unroll
      for (int kf = 0; kf < 4; ++kf) {
        f32x4 z = (f32x4){0.f,0.f,0.f,0.f};
        z = __builtin_amdgcn_mfma_f32_16x16x32_bf16(aq[mg][0], kf0[kf], z, 0, 0, 0);
        s[mg][kf] = __builtin_amdgcn_mfma_f32_16x16x32_bf16(aq[mg][1], kf1[kf], z, 0, 0, 0);
      }
    __builtin_amdgcn_s_setprio(0);
    // ---- max-free softmax: p = exp2(s), accumulate denominator per-lane
    #pragma unroll
    for (int mg = 0; mg < 2; ++mg)
      #pragma unroll
      for (int r = 0; r < 4; ++r) {
        float p0 = __builtin_exp2f(s[mg][0][r]);
        float p1 = __builtin_exp2f(s[mg][1][r]);
        float p2 = __builtin_exp2f(s[mg][2][r]);
        float p3 = __builtin_exp2f(s[mg][3][r]);
        l[mg][r] += (p0 + p1) + (p2 + p3);
        unsigned w0 = cvt_pk_bf16(p0, p1);
        unsigned w1 = cvt_pk_bf16(p2, p3);
        *(uint2*)&pt[w][mg*16 + (lane >> 4)*4 + r][(lane & 15)*4] = make_uint2(w0, w1);
      }
    // ---- PV (pi-permuted positions consistent between pt and vt)
    short8 pa[2][2];
    #pragma unroll
    for (int mg = 0; mg < 2; ++mg) {
      pa[mg][0] = *(const short8*)&pt[w][mg*16 + (lane & 15)][(lane >> 4)*8];
      pa[mg][1] = *(const short8*)&pt[w][mg*16 + (lane & 15)][32 + (lane >> 4)*8];
    }
    __builtin_amdgcn_s_setprio(1);
    #pragma unroll
    for (int df = 0; df < 4; ++df) {
      short8 v0 = *(const short8*)&vt[cur][df*16 + (lane & 15)][(lane >> 4)*8];
      short8 v1 = *(const short8*)&vt[cur][df*16 + (lane & 15)][32 + (lane >> 4)*8];
      o[0][df] = __builtin_amdgcn_mfma_f32_16x16x32_bf16(pa[0][0], v0, o[0][df], 0, 0, 0);
      o[0][df] = __builtin_amdgcn_mfma_f32_16x16x32_bf16(pa[0][1], v1, o[0][df], 0, 0, 0);
      o[1][df] = __builtin_amdgcn_mfma_f32_16x16x32_bf16(pa[1][0], v0, o[1][df], 0, 0, 0);
      o[1][df] = __builtin_amdgcn_mfma_f32_16x16x32_bf16(pa[1][1], v1, o[1][df], 0, 0, 0);
    }
    __builtin_amdgcn_s_setprio(0);
    // ---- single barrier per tile: publish next buffer, issue loads for t+2
    if (t < 31) {
      *(short8*)&kt[cur^1][srow][scol]     = kr0;
      *(short8*)&kt[cur^1][srow][scol + 8] = kr1;
      *(short8*)&vt[cur^1][srow][scol]     = vr0;
      *(short8*)&vt[cur^1][srow][scol + 8] = vr1;
      if (t < 30) {
        const int k2 = (t + 2) * 64;
        kr0 = *(const short8*)&kb[(size_t)(k2 + srow)*DH + scol];
        kr1 = *(const short8*)&kb[(size_t)(k2 + srow)*DH + scol + 8];
        vr0 = *(const short8*)&vb[(size_t)srow*NS + k2 + scol];
        vr1 = *(const short8*)&vb[(size_t)srow*NS + k2 + scol + 8];
      }
      __syncthreads();
    }
  }
  // final denominator reduce across the 16-lane column group
  #pragma unroll
  for (int mg = 0; mg < 2; ++mg)
    #pragma unroll
    for (int r = 0; r < 4; ++r) {
      float ls = l[mg][r];
      ls += __shfl_xor(ls, 1);
      ls += __shfl_xor(ls, 2);
      ls += __shfl_xor(ls, 4);
      ls += __shfl_xor(ls, 8);
      l[mg][r] = 1.f / ls;
    }
  #pragma unroll
  for (int mg = 0; mg < 2; ++mg)
    #pragma unroll
    for (int df = 0; df < 4; ++df) {
      const int col = h*DH + df*16 + (lane & 15);
      #pragma unroll
      for (int r = 0; r < 4; ++r) {
        const int n = q0 + w*32 + mg*16 + (lane >> 4)*4 + r;
        ao[((size_t)b*NS + n)*DIM + col] = f2bf(o[mg][df][r] * l[mg][r]);
      }
    }
}

// ---------- out GEMM: ao @ Woutt^T + xn + bout -> out (b,512,2048) f32
__global__ __launch_bounds__(256) void out_kernel(const unsigned short* __restrict__ A,
    const unsigned short* __restrict__ Bt, const unsigned short* __restrict__ xn,
    const float* __restrict__ bout, float* __restrict__ out) {
  __shared__ __align__(16) short As[128][40];
  __shared__ __align__(16) short Bs[128][40];
  const int m0 = blockIdx.x * 128, n0 = blockIdx.y * 128;
  const int tid = threadIdx.x, w = tid >> 6, lane = tid & 63;
  const int wr = w >> 1, wc = w & 1;
  f32x4 acc[4][4];
  #pragma unroll
  for (int i = 0; i < 4; ++i)
    #pragma unroll
    for (int j = 0; j < 4; ++j) acc[i][j] = (f32x4){0.f,0.f,0.f,0.f};
  const int rA = tid >> 2, c8 = (tid & 3) * 8;
  for (int kt = 0; kt < 16; ++kt) {
    short8 a0 = *(const short8*)&A[(size_t)(m0 + rA)*DIM + kt*32 + c8];
    short8 a1 = *(const short8*)&A[(size_t)(m0 + 64 + rA)*DIM + kt*32 + c8];
    short8 b0 = *(const short8*)&Bt[(size_t)(n0 + rA)*DIM + kt*32 + c8];
    short8 b1 = *(const short8*)&Bt[(size_t)(n0 + 64 + rA)*DIM + kt*32 + c8];
    *(short8*)&As[rA][c8] = a0;
    *(short8*)&As[64 + rA][c8] = a1;
    *(short8*)&Bs[rA][c8] = b0;
    *(short8*)&Bs[64 + rA][c8] = b1;
    __syncthreads();
    short8 af[4], bf[4];
    #pragma unroll
    for (int mf = 0; mf < 4; ++mf)
      af[mf] = *(const short8*)&As[wr*64 + mf*16 + (lane & 15)][(lane >> 4)*8];
    #pragma unroll
    for (int nf = 0; nf < 4; ++nf)
      bf[nf] = *(const short8*)&Bs[wc*64 + nf*16 + (lane & 15)][(lane >> 4)*8];
    #pragma unroll
    for (int mf = 0; mf < 4; ++mf)
      #pragma unroll
      for (int nf = 0; nf < 4; ++nf)
        acc[mf][nf] = __builtin_amdgcn_mfma_f32_16x16x32_bf16(af[mf], bf[nf], acc[mf][nf], 0, 0, 0);
    __syncthreads();
  }
  const int mw = m0 + wr*64, cw = n0 + wc*64;
  #pragma unroll
  for (int nf = 0; nf < 4; ++nf) {
    const int d = cw + nf*16 + (lane & 15);
    const float bo = bout[d];
    #pragma unroll
    for (int mf = 0; mf < 4; ++mf) {
      const int mb = mw + mf*16 + (lane >> 4)*4;
      const int bb = mb >> 11, n = mb & (NS-1);
      f32x4 res;
      #pragma unroll
      for (int r = 0; r < 4; ++r)
        res[r] = acc[mf][nf][r] + bf2f(xn[(size_t)(mb + r)*DIM + d]) + bo;
      *(f32x4*)&out[((size_t)bb*DIM + d)*NS + n] = res;
    }
  }
}

extern "C" void kernel_launch(void* const* d_in, const int* in_sizes, int n_in,
                              void* d_out, int out_size, void* d_ws, size_t ws_size,
                              hipStream_t stream) {
  (void)in_sizes; (void)n_in; (void)out_size; (void)ws_size;
  const float* x     = (const float*)d_in[0];
  const float* gamma = (const float*)d_in[1];
  const float* beta  = (const float*)d_in[2];
  const float* Wq    = (const float*)d_in[3];
  const float* Wkv   = (const float*)d_in[4];
  const float* Wout  = (const float*)d_in[5];
  const float* bout  = (const float*)d_in[6];
  float* out = (float*)d_out;
  char* ws = (char*)d_ws;
  unsigned short* xn    = (unsigned short*)(ws);                         // 8 MB
  unsigned short* qb    = (unsigned short*)(ws + (size_t)(8<<20));       // 8 MB
  unsigned short* kb    = (unsigned short*)(ws + (size_t)(16<<20));      // 2 MB
  unsigned short* vb    = (unsigned short*)(ws + (size_t)(18<<20));      // 2 MB (V^T, pi-permuted)
  unsigned short* ao    = (unsigned short*)(ws + (size_t)(20<<20));      // 8 MB
  unsigned short* wqkvt = (unsigned short*)(ws + (size_t)(28<<20));      // 768 KB
  unsigned short* woutt = (unsigned short*)(ws + (size_t)(28<<20) + 786432); // 512 KB
  float* tabs           = (float*)(ws + (size_t)(28<<20) + 786432 + 524288); // 1 MB

  ln_kernel<<<dim3(64, 4), dim3(256), 0, stream>>>(x, gamma, beta, xn);
  cvt_kernel<<<dim3(160), dim3(256), 0, stream>>>(Wq, Wkv, Wout, wqkvt, woutt);
  tables_kernel<<<dim3(256), dim3(256), 0, stream>>>(tabs);
  qkv_kernel<<<dim3(64, 6), dim3(256), 0, stream>>>(xn, wqkvt, tabs, qb, kb, vb);
  attn_kernel<<<dim3(512), dim3(256), 0, stream>>>(qb, kb, vb, ao);
  out_kernel<<<dim3(64, 4), dim3(256), 0, stream>>>(ao, woutt, xn, bout, out);
}